// Round 5
// baseline (2025.948 us; speedup 1.0000x reference)
//
#include <hip/hip_runtime.h>

#define D 128
#define BN_EPS 1e-5f

typedef _Float16 half8 __attribute__((ext_vector_type(8)));
typedef float f32x4 __attribute__((ext_vector_type(4)));
typedef unsigned short ushort_t;

// ---------------- fp16 pack/unpack helpers ----------------
__device__ __forceinline__ unsigned short f2h(float f) {
  union { _Float16 h; unsigned short u; } c;
  c.h = (_Float16)f;  // RNE
  return c.u;
}
__device__ __forceinline__ unsigned int packh(float lo, float hi) {
  return (unsigned int)f2h(lo) | ((unsigned int)f2h(hi) << 16);
}
__device__ __forceinline__ float h2f(unsigned int v) {
  union { unsigned short u; _Float16 h; } c;
  c.u = (unsigned short)v;
  return (float)c.h;
}

// ---------------------------------------------------------------------------
// Edge dtype sniffer (int64 vs int32 edge_index)
// ---------------------------------------------------------------------------
__global__ void k_detect(const int* __restrict__ ei, int* __restrict__ flag) {
  if (blockIdx.x == 0 && threadIdx.x == 0) {
    int is64 = 1;
    for (int i = 0; i < 16; i++)
      if (ei[2 * i + 1] != 0) is64 = 0;
    *flag = is64;
  }
}
__device__ __forceinline__ int load_src(const int* ei, int e, int i, int is64) {
  return is64 ? ei[2 * i] : ei[i];
}
__device__ __forceinline__ int load_dst(const int* ei, int e, int i, int is64) {
  return is64 ? ei[2 * e + 2 * i] : ei[e + i];
}

// ---------------------------------------------------------------------------
// Graph prep. CSR rows PADDED to a multiple of 16 (pad: col=0, wgt=0).
// ---------------------------------------------------------------------------
__global__ void k_hist(const int* __restrict__ ei, int* __restrict__ cnt,
                       const int* __restrict__ flag, int e) {
  int i = blockIdx.x * blockDim.x + threadIdx.x;
  if (i < e) {
    int d = load_dst(ei, e, i, *flag);
    atomicAdd(&cnt[d], 1);
  }
}

__global__ void k_scan1(const int* __restrict__ cnt, int* __restrict__ excl,
                        int* __restrict__ bsum, int n) {
  __shared__ int s[256];
  int t = threadIdx.x;
  int base = blockIdx.x * 1024;
  int v[4];
  int tot = 0;
#pragma unroll
  for (int i = 0; i < 4; i++) {
    int idx = base + t * 4 + i;
    v[i] = (idx < n) ? ((cnt[idx] + 15) & ~15) : 0;
    tot += v[i];
  }
  s[t] = tot;
  __syncthreads();
#pragma unroll
  for (int off = 1; off < 256; off <<= 1) {
    int x = (t >= off) ? s[t - off] : 0;
    __syncthreads();
    s[t] += x;
    __syncthreads();
  }
  int run = s[t] - tot;
#pragma unroll
  for (int i = 0; i < 4; i++) {
    int idx = base + t * 4 + i;
    if (idx < n) excl[idx] = run;
    run += v[i];
  }
  if (t == 255) bsum[blockIdx.x] = s[255];
}

__global__ void k_scan2(int* bsum, int nb, int* row_ptr, int n) {
  if (blockIdx.x == 0 && threadIdx.x == 0) {
    int run = 0;
    for (int i = 0; i < nb; i++) {
      int t = bsum[i];
      bsum[i] = run;
      run += t;
    }
    row_ptr[n] = run;
  }
}

__global__ void k_scan3(const int* __restrict__ excl, const int* __restrict__ bsum,
                        int* __restrict__ row_ptr, int n) {
  int i = blockIdx.x * blockDim.x + threadIdx.x;
  if (i < n) row_ptr[i] = excl[i] + bsum[i >> 10];
}

__global__ void k_dinv(const int* __restrict__ cnt, float* __restrict__ dinv, int n) {
  int i = blockIdx.x * blockDim.x + threadIdx.x;
  if (i < n) dinv[i] = rsqrtf((float)(cnt[i] + 1));  // +1 self loop
}

__global__ void k_scatter(const int* __restrict__ ei, const int* __restrict__ row_ptr,
                          int* __restrict__ fill, const float* __restrict__ dinv,
                          int* __restrict__ col, float* __restrict__ wgt,
                          const int* __restrict__ flag, int e) {
  int i = blockIdx.x * blockDim.x + threadIdx.x;
  if (i < e) {
    int is64 = *flag;
    int s = load_src(ei, e, i, is64);
    int d = load_dst(ei, e, i, is64);
    int pos = row_ptr[d] + atomicAdd(&fill[d], 1);
    col[pos] = s;
    wgt[pos] = dinv[s] * dinv[d];
  }
}

// ---------------------------------------------------------------------------
// W fp32 -> fp16 in MFMA-B-fragment-major layout: Wf[l][(k>>3)*128 + c][k&7]
// ---------------------------------------------------------------------------
__global__ void k_wconv(const float* __restrict__ W0, const float* __restrict__ Wmid,
                        const float* __restrict__ Wlast, ushort_t* __restrict__ Wf) {
  int i = blockIdx.x * 256 + threadIdx.x;
  if (i >= 6 * 16384) return;
  int l = i >> 14, r = i & 16383;
  int k = r >> 7, c = r & 127;
  const float* W = (l == 0) ? W0 : (l <= 4 ? Wmid + (size_t)(l - 1) * 16384 : Wlast);
  Wf[(size_t)l * 16384 + (((k >> 3) * 128 + c) << 3) + (k & 7)] = f2h(W[r]);
}

// ---------------------------------------------------------------------------
// Fused GEMM: x = epilogue(src) ; H = x @ W.
//   mode 0: x = fp32 src (raw input), no BN, no Xh write
//   mode 1: x = relu(bn(src_fp16)); write XhNew
//   mode 2: x = relu(bn(src_fp16)) + XhPrev; write XhNew
// BN coeffs computed per-thread from stats (each thread only stages channel
// octet t&15, so 8 sc + 8 sh live in registers). MFMA core: 128-row tile,
// 4 waves x 32 rows, frag-major LDS, 64 mfma_f32_16x16x32_f16 per wave.
// ---------------------------------------------------------------------------
__global__ __launch_bounds__(256) void k_gemm(
    const void* __restrict__ src, const ushort_t* __restrict__ Wf,
    ushort_t* __restrict__ Hh, unsigned int* __restrict__ XhNew,
    const unsigned int* __restrict__ XhPrev, const float* __restrict__ stats,
    const float* __restrict__ gamma, const float* __restrict__ beta, int n,
    int mode) {
  __shared__ ushort_t As[16384];
  __shared__ ushort_t Ws[16384];
  const int t = threadIdx.x;
  const int rowBase = blockIdx.x * 128;
  const int off = t & 15;  // channel octet this thread stages (all 8 chunks)

  float sc[8], sh[8];
  if (mode >= 1) {
    float inv_n = 1.0f / (float)n;
#pragma unroll
    for (int j = 0; j < 8; j++) {
      int ch = off * 8 + j;
      float mean = stats[ch] * inv_n;
      float var = stats[128 + ch] * inv_n - mean * mean;
      if (var < 0.f) var = 0.f;
      float is = rsqrtf(var + BN_EPS);
      float s = gamma[ch] * is;
      sc[j] = s;
      sh[j] = beta[ch] - mean * s;
    }
  }

#pragma unroll
  for (int i = 0; i < 8; i++) {
    int c = t + i * 256;
    int row = c >> 4;
    int grow = rowBase + row;
    bool valid = grow < n;
    if (!valid) grow = n - 1;
    unsigned int pk[4];
    if (mode == 0) {
      const float* xp = (const float*)src + (size_t)grow * 128 + off * 8;
      float4 v0 = *(const float4*)xp;
      float4 v1 = *(const float4*)(xp + 4);
      pk[0] = packh(v0.x, v0.y);
      pk[1] = packh(v0.z, v0.w);
      pk[2] = packh(v1.x, v1.y);
      pk[3] = packh(v1.z, v1.w);
    } else {
      const unsigned int* ap = (const unsigned int*)src + (size_t)grow * 64 + off * 4;
      uint4 av = *(const uint4*)ap;
      float v[8];
      v[0] = h2f(av.x & 0xffff); v[1] = h2f(av.x >> 16);
      v[2] = h2f(av.y & 0xffff); v[3] = h2f(av.y >> 16);
      v[4] = h2f(av.z & 0xffff); v[5] = h2f(av.z >> 16);
      v[6] = h2f(av.w & 0xffff); v[7] = h2f(av.w >> 16);
#pragma unroll
      for (int j = 0; j < 8; j++) v[j] = fmaxf(v[j] * sc[j] + sh[j], 0.f);
      if (mode == 2) {
        uint4 rv = *(const uint4*)(XhPrev + (size_t)grow * 64 + off * 4);
        v[0] += h2f(rv.x & 0xffff); v[1] += h2f(rv.x >> 16);
        v[2] += h2f(rv.y & 0xffff); v[3] += h2f(rv.y >> 16);
        v[4] += h2f(rv.z & 0xffff); v[5] += h2f(rv.z >> 16);
        v[6] += h2f(rv.w & 0xffff); v[7] += h2f(rv.w >> 16);
      }
      pk[0] = packh(v[0], v[1]);
      pk[1] = packh(v[2], v[3]);
      pk[2] = packh(v[4], v[5]);
      pk[3] = packh(v[6], v[7]);
      if (valid) *(uint4*)(XhNew + (size_t)grow * 64 + off * 4) = *(uint4*)pk;
    }
    *(uint4*)(&As[(off * 128 + row) * 8]) = *(uint4*)pk;
  }
#pragma unroll
  for (int i = 0; i < 8; i++) {
    int c = t + i * 256;
    *(uint4*)(&Ws[c * 8]) = *(const uint4*)(Wf + c * 8);
  }
  __syncthreads();

  const int wave = t >> 6, lane = t & 63;
  const int q = lane >> 4, ln = lane & 15;
  const int m0 = wave * 32;

  f32x4 acc[2][8];
#pragma unroll
  for (int mt = 0; mt < 2; mt++)
#pragma unroll
    for (int nt = 0; nt < 8; nt++) acc[mt][nt] = (f32x4){0.f, 0.f, 0.f, 0.f};

#pragma unroll
  for (int kk = 0; kk < 4; kk++) {
    int kg = kk * 4 + q;
    half8 a[2];
#pragma unroll
    for (int mt = 0; mt < 2; mt++)
      a[mt] = *(const half8*)(&As[(kg * 128 + m0 + mt * 16 + ln) * 8]);
    half8 b[8];
#pragma unroll
    for (int nt = 0; nt < 8; nt++)
      b[nt] = *(const half8*)(&Ws[(kg * 128 + nt * 16 + ln) * 8]);
#pragma unroll
    for (int mt = 0; mt < 2; mt++)
#pragma unroll
      for (int nt = 0; nt < 8; nt++)
        acc[mt][nt] =
            __builtin_amdgcn_mfma_f32_16x16x32_f16(a[mt], b[nt], acc[mt][nt], 0, 0, 0);
  }

#pragma unroll
  for (int mt = 0; mt < 2; mt++) {
#pragma unroll
    for (int r = 0; r < 4; r++) {
      int grow = rowBase + m0 + mt * 16 + q * 4 + r;
      if (grow < n) {
#pragma unroll
        for (int nt = 0; nt < 8; nt++)
          Hh[(size_t)grow * 128 + nt * 16 + ln] = f2h(acc[mt][nt][r]);
      }
    }
  }
}

// ---------------------------------------------------------------------------
// Aggregation over fp16-packed h, PAIRED-EDGE gathers: one wave per node;
// lanes 0-31 process even edges, lanes 32-63 odd edges; each lane loads
// dwordx2 (4 channels) -> 512 B per instruction spanning 2 rows. 16-edge
// groups = 8 gather instructions in flight; col/wgt (wave-uniform) prefetched
// one group ahead. Halves combined via shfl_xor(32) at node end.
// last=0: fp16-packed out + BN stats.  last=1: fp32 out, no stats.
// ---------------------------------------------------------------------------
__global__ __launch_bounds__(256) void k_agg(const unsigned int* __restrict__ hb,
                                             const int* __restrict__ row_ptr,
                                             const int* __restrict__ col,
                                             const float* __restrict__ wgt,
                                             const float* __restrict__ dinv,
                                             const float* __restrict__ bias,
                                             void* __restrict__ out,
                                             float* __restrict__ stats, int n,
                                             int last) {
  __shared__ float lsum[128], lsq[128];
  const int t = threadIdx.x;
  if (!last) {
    if (t < 128) {
      lsum[t] = 0.f;
      lsq[t] = 0.f;
    }
    __syncthreads();
  }
  const int wave = t >> 6, lane = t & 63;
  const int p = lane & 31;       // position within half (4 channels: 4p..4p+3)
  const int hi = lane >> 5;      // 0 = even edges, 1 = odd edges
  const uint2* hbp = (const uint2*)hb;

  for (int nd = blockIdx.x * 4 + wave; nd < n; nd += gridDim.x * 4) {
    float di = dinv[nd];
    float wself = hi ? 0.f : di * di;  // self-loop counted once (half 0)
    uint2 sv = hbp[(size_t)nd * 32 + p];
    float a0 = wself * h2f(sv.x & 0xffff), a1 = wself * h2f(sv.x >> 16);
    float a2 = wself * h2f(sv.y & 0xffff), a3 = wself * h2f(sv.y >> 16);
    int e0 = row_ptr[nd], e1 = row_ptr[nd + 1];  // length multiple of 16
    if (e0 < e1) {
      int sA[16];
      float wA[16];
#pragma unroll
      for (int j = 0; j < 16; j++) {
        sA[j] = col[e0 + j];
        wA[j] = wgt[e0 + j];
      }
      for (int e = e0; e < e1; e += 16) {
        int en = e + 16;
        int ep = (en < e1) ? en : e;
        int sB[16];
        float wB[16];
#pragma unroll
        for (int j = 0; j < 16; j++) {
          sB[j] = col[ep + j];
          wB[j] = wgt[ep + j];
        }
        uint2 u[8];
#pragma unroll
        for (int jj = 0; jj < 8; jj++) {
          int row = hi ? sA[2 * jj + 1] : sA[2 * jj];
          u[jj] = hbp[(size_t)row * 32 + p];
        }
#pragma unroll
        for (int jj = 0; jj < 8; jj++) {
          float w = hi ? wA[2 * jj + 1] : wA[2 * jj];
          a0 += w * h2f(u[jj].x & 0xffff);
          a1 += w * h2f(u[jj].x >> 16);
          a2 += w * h2f(u[jj].y & 0xffff);
          a3 += w * h2f(u[jj].y >> 16);
        }
#pragma unroll
        for (int j = 0; j < 16; j++) {
          sA[j] = sB[j];
          wA[j] = wB[j];
        }
      }
    }
    // combine odd/even halves
    a0 += __shfl_xor(a0, 32);
    a1 += __shfl_xor(a1, 32);
    a2 += __shfl_xor(a2, 32);
    a3 += __shfl_xor(a3, 32);
    if (!hi) {
      float4 bv = *(const float4*)(bias + p * 4);
      a0 += bv.x;
      a1 += bv.y;
      a2 += bv.z;
      a3 += bv.w;
      if (last) {
        float4 o = {a0, a1, a2, a3};
        *(float4*)((float*)out + (size_t)nd * 128 + p * 4) = o;
      } else {
        uint2 o;
        o.x = packh(a0, a1);
        o.y = packh(a2, a3);
        *(uint2*)((unsigned int*)out + (size_t)nd * 64 + p * 2) = o;
        atomicAdd(&lsum[p * 4 + 0], a0);
        atomicAdd(&lsum[p * 4 + 1], a1);
        atomicAdd(&lsum[p * 4 + 2], a2);
        atomicAdd(&lsum[p * 4 + 3], a3);
        atomicAdd(&lsq[p * 4 + 0], a0 * a0);
        atomicAdd(&lsq[p * 4 + 1], a1 * a1);
        atomicAdd(&lsq[p * 4 + 2], a2 * a2);
        atomicAdd(&lsq[p * 4 + 3], a3 * a3);
      }
    }
  }
  if (!last) {
    __syncthreads();
    if (t < 128) {
      atomicAdd(&stats[t], lsum[t]);
      atomicAdd(&stats[128 + t], lsq[t]);
    }
  }
}

// ---------------------------------------------------------------------------
extern "C" void kernel_launch(void* const* d_in, const int* in_sizes, int n_in,
                              void* d_out, int out_size, void* d_ws, size_t ws_size,
                              hipStream_t stream) {
  const float* x_in = (const float*)d_in[0];
  const int* ei = (const int*)d_in[1];
  const float* W0 = (const float*)d_in[2];
  const float* b0 = (const float*)d_in[3];
  const float* Wmid = (const float*)d_in[4];
  const float* bmid = (const float*)d_in[5];
  const float* Wlast = (const float*)d_in[6];
  const float* blast = (const float*)d_in[7];
  const float* gamma = (const float*)d_in[8];
  const float* beta = (const float*)d_in[9];

  const int n = in_sizes[0] / D;  // 100000
  const int e = in_sizes[1] / 2;  // 1600000
  const int ec = e + 16 * n;      // padded-edge capacity (worst case)

  // ---- workspace carve-out ----
  char* ws = (char*)d_ws;
  size_t off = 0;
  auto alloc = [&](size_t bytes) -> void* {
    void* p = ws + off;
    off += (bytes + 255) & ~(size_t)255;
    return p;
  };
  unsigned int* XhA = (unsigned int*)alloc((size_t)n * 64 * 4);  // fp16 x ping
  unsigned int* XhB = (unsigned int*)alloc((size_t)n * 64 * 4);  // fp16 x pong
  unsigned int* Hh = (unsigned int*)alloc((size_t)n * 64 * 4);   // fp16 h
  unsigned int* Ag = (unsigned int*)alloc((size_t)n * 64 * 4);   // fp16 aggout
  ushort_t* Wf = (ushort_t*)alloc((size_t)6 * 16384 * 2);
  int* row_ptr = (int*)alloc((size_t)(n + 1) * 4);
  int* excl = (int*)alloc((size_t)n * 4);
  float* dinv = (float*)alloc((size_t)n * 4);
  int* bsum = (int*)alloc(1024);
  int* flag = (int*)alloc(256);
  // zeroed region: col | wgt | cnt | fill | stats  (single memset)
  char* zbase = ws + off;
  int* col = (int*)alloc((size_t)ec * 4);
  float* wgt = (float*)alloc((size_t)ec * 4);
  int* cnt = (int*)alloc((size_t)n * 4);
  int* fill = (int*)alloc((size_t)n * 4);
  float* stats = (float*)alloc(5 * 256 * 4);
  size_t zbytes = (size_t)((ws + off) - zbase);
  hipMemsetAsync(zbase, 0, zbytes, stream);

  // ---- graph prep ----
  k_detect<<<1, 64, 0, stream>>>(ei, flag);
  int eb = (e + 255) / 256;
  k_hist<<<eb, 256, 0, stream>>>(ei, cnt, flag, e);
  int nb1024 = (n + 1023) / 1024;
  k_scan1<<<nb1024, 256, 0, stream>>>(cnt, excl, bsum, n);
  k_scan2<<<1, 64, 0, stream>>>(bsum, nb1024, row_ptr, n);
  int nb256 = (n + 255) / 256;
  k_scan3<<<nb256, 256, 0, stream>>>(excl, bsum, row_ptr, n);
  k_dinv<<<nb256, 256, 0, stream>>>(cnt, dinv, n);
  k_scatter<<<eb, 256, 0, stream>>>(ei, row_ptr, fill, dinv, col, wgt, flag, e);
  k_wconv<<<(6 * 16384 + 255) / 256, 256, 0, stream>>>(W0, Wmid, Wlast, Wf);

  // ---- layers ----
  const int gemm_blocks = (n + 127) / 128;
  const int agg_blocks = 2048;

  // layer 0
  k_gemm<<<gemm_blocks, 256, 0, stream>>>(x_in, Wf, (ushort_t*)Hh, nullptr,
                                          nullptr, nullptr, nullptr, nullptr, n, 0);
  k_agg<<<agg_blocks, 256, 0, stream>>>(Hh, row_ptr, col, wgt, dinv, b0, Ag,
                                        stats, n, 0);
  // layers 1..4 (gemm_L fuses BN/relu/residual of layer L-1)
  unsigned int* xprev = nullptr;
  unsigned int* xnew = XhA;
  for (int L = 1; L <= 4; L++) {
    const float* bL = bmid + (size_t)(L - 1) * D;
    k_gemm<<<gemm_blocks, 256, 0, stream>>>(
        Ag, Wf + (size_t)L * 16384, (ushort_t*)Hh, xnew, xprev,
        stats + (L - 1) * 256, gamma + (L - 1) * D, beta + (L - 1) * D, n,
        (L == 1) ? 1 : 2);
    k_agg<<<agg_blocks, 256, 0, stream>>>(Hh, row_ptr, col, wgt, dinv, bL, Ag,
                                          stats + L * 256, n, 0);
    xprev = xnew;
    xnew = (xnew == XhA) ? XhB : XhA;
  }
  // output layer (gemm_5 fuses BN/relu/residual of layer 4)
  k_gemm<<<gemm_blocks, 256, 0, stream>>>(Ag, Wf + (size_t)5 * 16384,
                                          (ushort_t*)Hh, xnew, xprev,
                                          stats + 4 * 256, gamma + 4 * D,
                                          beta + 4 * D, n, 2);
  k_agg<<<agg_blocks, 256, 0, stream>>>(Hh, row_ptr, col, wgt, dinv, blast,
                                        d_out, nullptr, n, 1);
}

// Round 6
// 1772.287 us; speedup vs baseline: 1.1431x; 1.1431x over previous
//
#include <hip/hip_runtime.h>

#define D 128
#define BN_EPS 1e-5f

typedef _Float16 half8 __attribute__((ext_vector_type(8)));
typedef float f32x4 __attribute__((ext_vector_type(4)));
typedef unsigned short ushort_t;

// ---------------- fp16 pack/unpack helpers ----------------
__device__ __forceinline__ unsigned short f2h(float f) {
  union { _Float16 h; unsigned short u; } c;
  c.h = (_Float16)f;  // RNE
  return c.u;
}
__device__ __forceinline__ unsigned int packh(float lo, float hi) {
  return (unsigned int)f2h(lo) | ((unsigned int)f2h(hi) << 16);
}
__device__ __forceinline__ float h2f(unsigned int v) {
  union { unsigned short u; _Float16 h; } c;
  c.u = (unsigned short)v;
  return (float)c.h;
}

// ---------------------------------------------------------------------------
// Edge dtype sniffer (int64 vs int32 edge_index)
// ---------------------------------------------------------------------------
__global__ void k_detect(const int* __restrict__ ei, int* __restrict__ flag) {
  if (blockIdx.x == 0 && threadIdx.x == 0) {
    int is64 = 1;
    for (int i = 0; i < 16; i++)
      if (ei[2 * i + 1] != 0) is64 = 0;
    *flag = is64;
  }
}
__device__ __forceinline__ int load_src(const int* ei, int e, int i, int is64) {
  return is64 ? ei[2 * i] : ei[i];
}
__device__ __forceinline__ int load_dst(const int* ei, int e, int i, int is64) {
  return is64 ? ei[2 * e + 2 * i] : ei[e + i];
}

// ---------------------------------------------------------------------------
// Graph prep. CSR rows PADDED to a multiple of 8 (pad: col=0, wgt=0).
// ---------------------------------------------------------------------------
__global__ void k_hist(const int* __restrict__ ei, int* __restrict__ cnt,
                       const int* __restrict__ flag, int e) {
  int i = blockIdx.x * blockDim.x + threadIdx.x;
  if (i < e) {
    int d = load_dst(ei, e, i, *flag);
    atomicAdd(&cnt[d], 1);
  }
}

__global__ void k_scan1(const int* __restrict__ cnt, int* __restrict__ excl,
                        int* __restrict__ bsum, int n) {
  __shared__ int s[256];
  int t = threadIdx.x;
  int base = blockIdx.x * 1024;
  int v[4];
  int tot = 0;
#pragma unroll
  for (int i = 0; i < 4; i++) {
    int idx = base + t * 4 + i;
    v[i] = (idx < n) ? ((cnt[idx] + 7) & ~7) : 0;
    tot += v[i];
  }
  s[t] = tot;
  __syncthreads();
#pragma unroll
  for (int off = 1; off < 256; off <<= 1) {
    int x = (t >= off) ? s[t - off] : 0;
    __syncthreads();
    s[t] += x;
    __syncthreads();
  }
  int run = s[t] - tot;
#pragma unroll
  for (int i = 0; i < 4; i++) {
    int idx = base + t * 4 + i;
    if (idx < n) excl[idx] = run;
    run += v[i];
  }
  if (t == 255) bsum[blockIdx.x] = s[255];
}

__global__ void k_scan2(int* bsum, int nb, int* row_ptr, int n) {
  if (blockIdx.x == 0 && threadIdx.x == 0) {
    int run = 0;
    for (int i = 0; i < nb; i++) {
      int t = bsum[i];
      bsum[i] = run;
      run += t;
    }
    row_ptr[n] = run;
  }
}

__global__ void k_scan3(const int* __restrict__ excl, const int* __restrict__ bsum,
                        int* __restrict__ row_ptr, int n) {
  int i = blockIdx.x * blockDim.x + threadIdx.x;
  if (i < n) row_ptr[i] = excl[i] + bsum[i >> 10];
}

__global__ void k_dinv(const int* __restrict__ cnt, float* __restrict__ dinv, int n) {
  int i = blockIdx.x * blockDim.x + threadIdx.x;
  if (i < n) dinv[i] = rsqrtf((float)(cnt[i] + 1));  // +1 self loop
}

__global__ void k_scatter(const int* __restrict__ ei, const int* __restrict__ row_ptr,
                          int* __restrict__ fill, const float* __restrict__ dinv,
                          int* __restrict__ col, float* __restrict__ wgt,
                          const int* __restrict__ flag, int e) {
  int i = blockIdx.x * blockDim.x + threadIdx.x;
  if (i < e) {
    int is64 = *flag;
    int s = load_src(ei, e, i, is64);
    int d = load_dst(ei, e, i, is64);
    int pos = row_ptr[d] + atomicAdd(&fill[d], 1);
    col[pos] = s;
    wgt[pos] = dinv[s] * dinv[d];
  }
}

// ---------------------------------------------------------------------------
// W fp32 -> fp16 in MFMA-B-fragment-major layout: Wf[l][(k>>3)*128 + c][k&7]
// ---------------------------------------------------------------------------
__global__ void k_wconv(const float* __restrict__ W0, const float* __restrict__ Wmid,
                        const float* __restrict__ Wlast, ushort_t* __restrict__ Wf) {
  int i = blockIdx.x * 256 + threadIdx.x;
  if (i >= 6 * 16384) return;
  int l = i >> 14, r = i & 16383;
  int k = r >> 7, c = r & 127;
  const float* W = (l == 0) ? W0 : (l <= 4 ? Wmid + (size_t)(l - 1) * 16384 : Wlast);
  Wf[(size_t)l * 16384 + (((k >> 3) * 128 + c) << 3) + (k & 7)] = f2h(W[r]);
}

// ---------------------------------------------------------------------------
// Fused GEMM: x = epilogue(src) ; H = x @ W.
//   mode 0: x = fp32 src (raw input), no BN, no Xh write
//   mode 1: x = relu(bn(src_fp16)); write XhNew
//   mode 2: x = relu(bn(src_fp16)) + XhPrev; write XhNew
// ---------------------------------------------------------------------------
__global__ __launch_bounds__(256) void k_gemm(
    const void* __restrict__ src, const ushort_t* __restrict__ Wf,
    ushort_t* __restrict__ Hh, unsigned int* __restrict__ XhNew,
    const unsigned int* __restrict__ XhPrev, const float* __restrict__ stats,
    const float* __restrict__ gamma, const float* __restrict__ beta, int n,
    int mode) {
  __shared__ ushort_t As[16384];
  __shared__ ushort_t Ws[16384];
  const int t = threadIdx.x;
  const int rowBase = blockIdx.x * 128;
  const int off = t & 15;  // channel octet this thread stages (all 8 chunks)

  float sc[8], sh[8];
  if (mode >= 1) {
    float inv_n = 1.0f / (float)n;
#pragma unroll
    for (int j = 0; j < 8; j++) {
      int ch = off * 8 + j;
      float mean = stats[ch] * inv_n;
      float var = stats[128 + ch] * inv_n - mean * mean;
      if (var < 0.f) var = 0.f;
      float is = rsqrtf(var + BN_EPS);
      float s = gamma[ch] * is;
      sc[j] = s;
      sh[j] = beta[ch] - mean * s;
    }
  }

#pragma unroll
  for (int i = 0; i < 8; i++) {
    int c = t + i * 256;
    int row = c >> 4;
    int grow = rowBase + row;
    bool valid = grow < n;
    if (!valid) grow = n - 1;
    unsigned int pk[4];
    if (mode == 0) {
      const float* xp = (const float*)src + (size_t)grow * 128 + off * 8;
      float4 v0 = *(const float4*)xp;
      float4 v1 = *(const float4*)(xp + 4);
      pk[0] = packh(v0.x, v0.y);
      pk[1] = packh(v0.z, v0.w);
      pk[2] = packh(v1.x, v1.y);
      pk[3] = packh(v1.z, v1.w);
    } else {
      const unsigned int* ap = (const unsigned int*)src + (size_t)grow * 64 + off * 4;
      uint4 av = *(const uint4*)ap;
      float v[8];
      v[0] = h2f(av.x & 0xffff); v[1] = h2f(av.x >> 16);
      v[2] = h2f(av.y & 0xffff); v[3] = h2f(av.y >> 16);
      v[4] = h2f(av.z & 0xffff); v[5] = h2f(av.z >> 16);
      v[6] = h2f(av.w & 0xffff); v[7] = h2f(av.w >> 16);
#pragma unroll
      for (int j = 0; j < 8; j++) v[j] = fmaxf(v[j] * sc[j] + sh[j], 0.f);
      if (mode == 2) {
        uint4 rv = *(const uint4*)(XhPrev + (size_t)grow * 64 + off * 4);
        v[0] += h2f(rv.x & 0xffff); v[1] += h2f(rv.x >> 16);
        v[2] += h2f(rv.y & 0xffff); v[3] += h2f(rv.y >> 16);
        v[4] += h2f(rv.z & 0xffff); v[5] += h2f(rv.z >> 16);
        v[6] += h2f(rv.w & 0xffff); v[7] += h2f(rv.w >> 16);
      }
      pk[0] = packh(v[0], v[1]);
      pk[1] = packh(v[2], v[3]);
      pk[2] = packh(v[4], v[5]);
      pk[3] = packh(v[6], v[7]);
      if (valid) *(uint4*)(XhNew + (size_t)grow * 64 + off * 4) = *(uint4*)pk;
    }
    *(uint4*)(&As[(off * 128 + row) * 8]) = *(uint4*)pk;
  }
#pragma unroll
  for (int i = 0; i < 8; i++) {
    int c = t + i * 256;
    *(uint4*)(&Ws[c * 8]) = *(const uint4*)(Wf + c * 8);
  }
  __syncthreads();

  const int wave = t >> 6, lane = t & 63;
  const int q = lane >> 4, ln = lane & 15;
  const int m0 = wave * 32;

  f32x4 acc[2][8];
#pragma unroll
  for (int mt = 0; mt < 2; mt++)
#pragma unroll
    for (int nt = 0; nt < 8; nt++) acc[mt][nt] = (f32x4){0.f, 0.f, 0.f, 0.f};

#pragma unroll
  for (int kk = 0; kk < 4; kk++) {
    int kg = kk * 4 + q;
    half8 a[2];
#pragma unroll
    for (int mt = 0; mt < 2; mt++)
      a[mt] = *(const half8*)(&As[(kg * 128 + m0 + mt * 16 + ln) * 8]);
    half8 b[8];
#pragma unroll
    for (int nt = 0; nt < 8; nt++)
      b[nt] = *(const half8*)(&Ws[(kg * 128 + nt * 16 + ln) * 8]);
#pragma unroll
    for (int mt = 0; mt < 2; mt++)
#pragma unroll
      for (int nt = 0; nt < 8; nt++)
        acc[mt][nt] =
            __builtin_amdgcn_mfma_f32_16x16x32_f16(a[mt], b[nt], acc[mt][nt], 0, 0, 0);
  }

#pragma unroll
  for (int mt = 0; mt < 2; mt++) {
#pragma unroll
    for (int r = 0; r < 4; r++) {
      int grow = rowBase + m0 + mt * 16 + q * 4 + r;
      if (grow < n) {
#pragma unroll
        for (int nt = 0; nt < 8; nt++)
          Hh[(size_t)grow * 128 + nt * 16 + ln] = f2h(acc[mt][nt][r]);
      }
    }
  }
}

// ---------------------------------------------------------------------------
// Aggregation over fp16-packed h, PAIRED-EDGE gathers, 8-edge groups:
// one wave per node; lanes 0-31 take even edges, lanes 32-63 odd edges;
// each lane loads uint2 (4 channels) -> each gather instruction moves 512 B
// across 2 rows. 4 gathers in flight per group; next group's col/wgt
// prefetched via 8-element arrays (NO 16-element arrays — those spill to
// LDS/scratch on gfx950, see R5). Halves combined via shfl_xor(32).
// last=0: fp16-packed out + BN stats.  last=1: fp32 out, no stats.
// ---------------------------------------------------------------------------
__global__ __launch_bounds__(256) void k_agg(const unsigned int* __restrict__ hb,
                                             const int* __restrict__ row_ptr,
                                             const int* __restrict__ col,
                                             const float* __restrict__ wgt,
                                             const float* __restrict__ dinv,
                                             const float* __restrict__ bias,
                                             void* __restrict__ out,
                                             float* __restrict__ stats, int n,
                                             int last) {
  __shared__ float lsum[128], lsq[128];
  const int t = threadIdx.x;
  if (!last) {
    if (t < 128) {
      lsum[t] = 0.f;
      lsq[t] = 0.f;
    }
    __syncthreads();
  }
  const int wave = t >> 6, lane = t & 63;
  const int p = lane & 31;   // position within half (channels 4p..4p+3)
  const int hi = lane >> 5;  // 0 = even edges, 1 = odd edges
  const uint2* hbp = (const uint2*)hb;

  for (int nd = blockIdx.x * 4 + wave; nd < n; nd += gridDim.x * 4) {
    float di = dinv[nd];
    float wself = hi ? 0.f : di * di;  // self-loop counted once (half 0)
    uint2 sv = hbp[(size_t)nd * 32 + p];
    float a0 = wself * h2f(sv.x & 0xffff), a1 = wself * h2f(sv.x >> 16);
    float a2 = wself * h2f(sv.y & 0xffff), a3 = wself * h2f(sv.y >> 16);
    int e0 = row_ptr[nd], e1 = row_ptr[nd + 1];  // length multiple of 8
    if (e0 < e1) {
      int sA[8];
      float wA[8];
#pragma unroll
      for (int j = 0; j < 8; j++) {
        sA[j] = col[e0 + j];
        wA[j] = wgt[e0 + j];
      }
      for (int e = e0; e < e1; e += 8) {
        int en = e + 8;
        int ep = (en < e1) ? en : e;  // clamp: reload current group if last
        int sB[8];
        float wB[8];
#pragma unroll
        for (int j = 0; j < 8; j++) {
          sB[j] = col[ep + j];
          wB[j] = wgt[ep + j];
        }
        uint2 u[4];
#pragma unroll
        for (int jj = 0; jj < 4; jj++) {
          int row = hi ? sA[2 * jj + 1] : sA[2 * jj];
          u[jj] = hbp[(size_t)row * 32 + p];
        }
#pragma unroll
        for (int jj = 0; jj < 4; jj++) {
          float w = hi ? wA[2 * jj + 1] : wA[2 * jj];
          a0 += w * h2f(u[jj].x & 0xffff);
          a1 += w * h2f(u[jj].x >> 16);
          a2 += w * h2f(u[jj].y & 0xffff);
          a3 += w * h2f(u[jj].y >> 16);
        }
#pragma unroll
        for (int j = 0; j < 8; j++) {
          sA[j] = sB[j];
          wA[j] = wB[j];
        }
      }
    }
    // combine odd/even halves
    a0 += __shfl_xor(a0, 32);
    a1 += __shfl_xor(a1, 32);
    a2 += __shfl_xor(a2, 32);
    a3 += __shfl_xor(a3, 32);
    if (!hi) {
      float4 bv = *(const float4*)(bias + p * 4);
      a0 += bv.x;
      a1 += bv.y;
      a2 += bv.z;
      a3 += bv.w;
      if (last) {
        float4 o = {a0, a1, a2, a3};
        *(float4*)((float*)out + (size_t)nd * 128 + p * 4) = o;
      } else {
        uint2 o;
        o.x = packh(a0, a1);
        o.y = packh(a2, a3);
        *(uint2*)((unsigned int*)out + (size_t)nd * 64 + p * 2) = o;
        atomicAdd(&lsum[p * 4 + 0], a0);
        atomicAdd(&lsum[p * 4 + 1], a1);
        atomicAdd(&lsum[p * 4 + 2], a2);
        atomicAdd(&lsum[p * 4 + 3], a3);
        atomicAdd(&lsq[p * 4 + 0], a0 * a0);
        atomicAdd(&lsq[p * 4 + 1], a1 * a1);
        atomicAdd(&lsq[p * 4 + 2], a2 * a2);
        atomicAdd(&lsq[p * 4 + 3], a3 * a3);
      }
    }
  }
  if (!last) {
    __syncthreads();
    if (t < 128) {
      atomicAdd(&stats[t], lsum[t]);
      atomicAdd(&stats[128 + t], lsq[t]);
    }
  }
}

// ---------------------------------------------------------------------------
extern "C" void kernel_launch(void* const* d_in, const int* in_sizes, int n_in,
                              void* d_out, int out_size, void* d_ws, size_t ws_size,
                              hipStream_t stream) {
  const float* x_in = (const float*)d_in[0];
  const int* ei = (const int*)d_in[1];
  const float* W0 = (const float*)d_in[2];
  const float* b0 = (const float*)d_in[3];
  const float* Wmid = (const float*)d_in[4];
  const float* bmid = (const float*)d_in[5];
  const float* Wlast = (const float*)d_in[6];
  const float* blast = (const float*)d_in[7];
  const float* gamma = (const float*)d_in[8];
  const float* beta = (const float*)d_in[9];

  const int n = in_sizes[0] / D;  // 100000
  const int e = in_sizes[1] / 2;  // 1600000
  const int ec = e + 8 * n;       // padded-edge capacity (worst case)

  // ---- workspace carve-out ----
  char* ws = (char*)d_ws;
  size_t off = 0;
  auto alloc = [&](size_t bytes) -> void* {
    void* p = ws + off;
    off += (bytes + 255) & ~(size_t)255;
    return p;
  };
  unsigned int* XhA = (unsigned int*)alloc((size_t)n * 64 * 4);  // fp16 x ping
  unsigned int* XhB = (unsigned int*)alloc((size_t)n * 64 * 4);  // fp16 x pong
  unsigned int* Hh = (unsigned int*)alloc((size_t)n * 64 * 4);   // fp16 h
  unsigned int* Ag = (unsigned int*)alloc((size_t)n * 64 * 4);   // fp16 aggout
  ushort_t* Wf = (ushort_t*)alloc((size_t)6 * 16384 * 2);
  int* row_ptr = (int*)alloc((size_t)(n + 1) * 4);
  int* excl = (int*)alloc((size_t)n * 4);
  float* dinv = (float*)alloc((size_t)n * 4);
  int* bsum = (int*)alloc(1024);
  int* flag = (int*)alloc(256);
  // zeroed region: col | wgt | cnt | fill | stats  (single memset)
  char* zbase = ws + off;
  int* col = (int*)alloc((size_t)ec * 4);
  float* wgt = (float*)alloc((size_t)ec * 4);
  int* cnt = (int*)alloc((size_t)n * 4);
  int* fill = (int*)alloc((size_t)n * 4);
  float* stats = (float*)alloc(5 * 256 * 4);
  size_t zbytes = (size_t)((ws + off) - zbase);
  hipMemsetAsync(zbase, 0, zbytes, stream);

  // ---- graph prep ----
  k_detect<<<1, 64, 0, stream>>>(ei, flag);
  int eb = (e + 255) / 256;
  k_hist<<<eb, 256, 0, stream>>>(ei, cnt, flag, e);
  int nb1024 = (n + 1023) / 1024;
  k_scan1<<<nb1024, 256, 0, stream>>>(cnt, excl, bsum, n);
  k_scan2<<<1, 64, 0, stream>>>(bsum, nb1024, row_ptr, n);
  int nb256 = (n + 255) / 256;
  k_scan3<<<nb256, 256, 0, stream>>>(excl, bsum, row_ptr, n);
  k_dinv<<<nb256, 256, 0, stream>>>(cnt, dinv, n);
  k_scatter<<<eb, 256, 0, stream>>>(ei, row_ptr, fill, dinv, col, wgt, flag, e);
  k_wconv<<<(6 * 16384 + 255) / 256, 256, 0, stream>>>(W0, Wmid, Wlast, Wf);

  // ---- layers ----
  const int gemm_blocks = (n + 127) / 128;
  const int agg_blocks = 2048;

  // layer 0
  k_gemm<<<gemm_blocks, 256, 0, stream>>>(x_in, Wf, (ushort_t*)Hh, nullptr,
                                          nullptr, nullptr, nullptr, nullptr, n, 0);
  k_agg<<<agg_blocks, 256, 0, stream>>>(Hh, row_ptr, col, wgt, dinv, b0, Ag,
                                        stats, n, 0);
  // layers 1..4 (gemm_L fuses BN/relu/residual of layer L-1)
  unsigned int* xprev = nullptr;
  unsigned int* xnew = XhA;
  for (int L = 1; L <= 4; L++) {
    const float* bL = bmid + (size_t)(L - 1) * D;
    k_gemm<<<gemm_blocks, 256, 0, stream>>>(
        Ag, Wf + (size_t)L * 16384, (ushort_t*)Hh, xnew, xprev,
        stats + (L - 1) * 256, gamma + (L - 1) * D, beta + (L - 1) * D, n,
        (L == 1) ? 1 : 2);
    k_agg<<<agg_blocks, 256, 0, stream>>>(Hh, row_ptr, col, wgt, dinv, bL, Ag,
                                          stats + L * 256, n, 0);
    xprev = xnew;
    xnew = (xnew == XhA) ? XhB : XhA;
  }
  // output layer (gemm_5 fuses BN/relu/residual of layer 4)
  k_gemm<<<gemm_blocks, 256, 0, stream>>>(Ag, Wf + (size_t)5 * 16384,
                                          (ushort_t*)Hh, xnew, xprev,
                                          stats + 4 * 256, gamma + 4 * D,
                                          beta + 4 * D, n, 2);
  k_agg<<<agg_blocks, 256, 0, stream>>>(Hh, row_ptr, col, wgt, dinv, blast,
                                        d_out, nullptr, n, 1);
}

// Round 8
// 1272.600 us; speedup vs baseline: 1.5920x; 1.3927x over previous
//
#include <hip/hip_runtime.h>

#define D 128
#define BN_EPS 1e-5f

typedef _Float16 half8 __attribute__((ext_vector_type(8)));
typedef float f32x4 __attribute__((ext_vector_type(4)));
typedef unsigned short ushort_t;

// ---------------- fp16 pack/unpack helpers ----------------
__device__ __forceinline__ unsigned short f2h(float f) {
  union { _Float16 h; unsigned short u; } c;
  c.h = (_Float16)f;  // RNE
  return c.u;
}
__device__ __forceinline__ unsigned int packh(float lo, float hi) {
  return (unsigned int)f2h(lo) | ((unsigned int)f2h(hi) << 16);
}
__device__ __forceinline__ float h2f(unsigned int v) {
  union { unsigned short u; _Float16 h; } c;
  c.u = (unsigned short)v;
  return (float)c.h;
}

// ---------------------------------------------------------------------------
// Edge dtype sniffer (int64 vs int32 edge_index)
// ---------------------------------------------------------------------------
__global__ void k_detect(const int* __restrict__ ei, int* __restrict__ flag) {
  if (blockIdx.x == 0 && threadIdx.x == 0) {
    int is64 = 1;
    for (int i = 0; i < 16; i++)
      if (ei[2 * i + 1] != 0) is64 = 0;
    *flag = is64;
  }
}
__device__ __forceinline__ int load_src(const int* ei, int e, int i, int is64) {
  return is64 ? ei[2 * i] : ei[i];
}
__device__ __forceinline__ int load_dst(const int* ei, int e, int i, int is64) {
  return is64 ? ei[2 * e + 2 * i] : ei[e + i];
}

// ---------------------------------------------------------------------------
// Graph prep. CSR rows PADDED to a multiple of 8 (pad: col=0, wgt=0).
// ---------------------------------------------------------------------------
__global__ void k_hist(const int* __restrict__ ei, int* __restrict__ cnt,
                       const int* __restrict__ flag, int e) {
  int i = blockIdx.x * blockDim.x + threadIdx.x;
  if (i < e) {
    int d = load_dst(ei, e, i, *flag);
    atomicAdd(&cnt[d], 1);
  }
}

__global__ void k_scan1(const int* __restrict__ cnt, int* __restrict__ excl,
                        int* __restrict__ bsum, int n) {
  __shared__ int s[256];
  int t = threadIdx.x;
  int base = blockIdx.x * 1024;
  int v[4];
  int tot = 0;
#pragma unroll
  for (int i = 0; i < 4; i++) {
    int idx = base + t * 4 + i;
    v[i] = (idx < n) ? ((cnt[idx] + 7) & ~7) : 0;
    tot += v[i];
  }
  s[t] = tot;
  __syncthreads();
#pragma unroll
  for (int off = 1; off < 256; off <<= 1) {
    int x = (t >= off) ? s[t - off] : 0;
    __syncthreads();
    s[t] += x;
    __syncthreads();
  }
  int run = s[t] - tot;
#pragma unroll
  for (int i = 0; i < 4; i++) {
    int idx = base + t * 4 + i;
    if (idx < n) excl[idx] = run;
    run += v[i];
  }
  if (t == 255) bsum[blockIdx.x] = s[255];
}

__global__ void k_scan2(int* bsum, int nb, int* row_ptr, int n) {
  if (blockIdx.x == 0 && threadIdx.x == 0) {
    int run = 0;
    for (int i = 0; i < nb; i++) {
      int t = bsum[i];
      bsum[i] = run;
      run += t;
    }
    row_ptr[n] = run;
  }
}

__global__ void k_scan3(const int* __restrict__ excl, const int* __restrict__ bsum,
                        int* __restrict__ row_ptr, int n) {
  int i = blockIdx.x * blockDim.x + threadIdx.x;
  if (i < n) row_ptr[i] = excl[i] + bsum[i >> 10];
}

__global__ void k_dinv(const int* __restrict__ cnt, float* __restrict__ dinv, int n) {
  int i = blockIdx.x * blockDim.x + threadIdx.x;
  if (i < n) dinv[i] = rsqrtf((float)(cnt[i] + 1));  // +1 self loop
}

__global__ void k_scatter(const int* __restrict__ ei, const int* __restrict__ row_ptr,
                          int* __restrict__ fill, const float* __restrict__ dinv,
                          int* __restrict__ col, float* __restrict__ wgt,
                          const int* __restrict__ flag, int e) {
  int i = blockIdx.x * blockDim.x + threadIdx.x;
  if (i < e) {
    int is64 = *flag;
    int s = load_src(ei, e, i, is64);
    int d = load_dst(ei, e, i, is64);
    int pos = row_ptr[d] + atomicAdd(&fill[d], 1);
    col[pos] = s;
    wgt[pos] = dinv[s] * dinv[d];
  }
}

// ---------------------------------------------------------------------------
// W fp32 -> fp16 in MFMA-B-fragment-major layout: Wf[l][(k>>3)*128 + c][k&7]
// ---------------------------------------------------------------------------
__global__ void k_wconv(const float* __restrict__ W0, const float* __restrict__ Wmid,
                        const float* __restrict__ Wlast, ushort_t* __restrict__ Wf) {
  int i = blockIdx.x * 256 + threadIdx.x;
  if (i >= 6 * 16384) return;
  int l = i >> 14, r = i & 16383;
  int k = r >> 7, c = r & 127;
  const float* W = (l == 0) ? W0 : (l <= 4 ? Wmid + (size_t)(l - 1) * 16384 : Wlast);
  Wf[(size_t)l * 16384 + (((k >> 3) * 128 + c) << 3) + (k & 7)] = f2h(W[r]);
}

// ---------------------------------------------------------------------------
// Fused GEMM: x = epilogue(src) ; H = x @ W.  (proven R5-R7 structure)
//   mode 0: x = fp32 src (raw input), no BN, no Xh write
//   mode 1: x = relu(bn(src_fp16)); write XhNew
//   mode 2: x = relu(bn(src_fp16)) + XhPrev; write XhNew
// ---------------------------------------------------------------------------
__global__ __launch_bounds__(256) void k_gemm(
    const void* __restrict__ src, const ushort_t* __restrict__ Wf,
    ushort_t* __restrict__ Hh, unsigned int* __restrict__ XhNew,
    const unsigned int* __restrict__ XhPrev, const float* __restrict__ stats,
    const float* __restrict__ gamma, const float* __restrict__ beta, int n,
    int mode) {
  __shared__ ushort_t As[16384];
  __shared__ ushort_t Ws[16384];
  const int t = threadIdx.x;
  const int rowBase = blockIdx.x * 128;
  const int off = t & 15;  // channel octet this thread stages (all 8 chunks)

  float sc[8], sh[8];
  if (mode >= 1) {
    float inv_n = 1.0f / (float)n;
#pragma unroll
    for (int j = 0; j < 8; j++) {
      int ch = off * 8 + j;
      float mean = stats[ch] * inv_n;
      float var = stats[128 + ch] * inv_n - mean * mean;
      if (var < 0.f) var = 0.f;
      float is = rsqrtf(var + BN_EPS);
      float s = gamma[ch] * is;
      sc[j] = s;
      sh[j] = beta[ch] - mean * s;
    }
  }

#pragma unroll
  for (int i = 0; i < 8; i++) {
    int c = t + i * 256;
    int row = c >> 4;
    int grow = rowBase + row;
    bool valid = grow < n;
    if (!valid) grow = n - 1;
    unsigned int pk[4];
    if (mode == 0) {
      const float* xp = (const float*)src + (size_t)grow * 128 + off * 8;
      float4 v0 = *(const float4*)xp;
      float4 v1 = *(const float4*)(xp + 4);
      pk[0] = packh(v0.x, v0.y);
      pk[1] = packh(v0.z, v0.w);
      pk[2] = packh(v1.x, v1.y);
      pk[3] = packh(v1.z, v1.w);
    } else {
      const unsigned int* ap = (const unsigned int*)src + (size_t)grow * 64 + off * 4;
      uint4 av = *(const uint4*)ap;
      float v[8];
      v[0] = h2f(av.x & 0xffff); v[1] = h2f(av.x >> 16);
      v[2] = h2f(av.y & 0xffff); v[3] = h2f(av.y >> 16);
      v[4] = h2f(av.z & 0xffff); v[5] = h2f(av.z >> 16);
      v[6] = h2f(av.w & 0xffff); v[7] = h2f(av.w >> 16);
#pragma unroll
      for (int j = 0; j < 8; j++) v[j] = fmaxf(v[j] * sc[j] + sh[j], 0.f);
      if (mode == 2) {
        uint4 rv = *(const uint4*)(XhPrev + (size_t)grow * 64 + off * 4);
        v[0] += h2f(rv.x & 0xffff); v[1] += h2f(rv.x >> 16);
        v[2] += h2f(rv.y & 0xffff); v[3] += h2f(rv.y >> 16);
        v[4] += h2f(rv.z & 0xffff); v[5] += h2f(rv.z >> 16);
        v[6] += h2f(rv.w & 0xffff); v[7] += h2f(rv.w >> 16);
      }
      pk[0] = packh(v[0], v[1]);
      pk[1] = packh(v[2], v[3]);
      pk[2] = packh(v[4], v[5]);
      pk[3] = packh(v[6], v[7]);
      if (valid) *(uint4*)(XhNew + (size_t)grow * 64 + off * 4) = *(uint4*)pk;
    }
    *(uint4*)(&As[(off * 128 + row) * 8]) = *(uint4*)pk;
  }
#pragma unroll
  for (int i = 0; i < 8; i++) {
    int c = t + i * 256;
    *(uint4*)(&Ws[c * 8]) = *(const uint4*)(Wf + c * 8);
  }
  __syncthreads();

  const int wave = t >> 6, lane = t & 63;
  const int q = lane >> 4, ln = lane & 15;
  const int m0 = wave * 32;

  f32x4 acc[2][8];
#pragma unroll
  for (int mt = 0; mt < 2; mt++)
#pragma unroll
    for (int nt = 0; nt < 8; nt++) acc[mt][nt] = (f32x4){0.f, 0.f, 0.f, 0.f};

#pragma unroll
  for (int kk = 0; kk < 4; kk++) {
    int kg = kk * 4 + q;
    half8 a[2];
#pragma unroll
    for (int mt = 0; mt < 2; mt++)
      a[mt] = *(const half8*)(&As[(kg * 128 + m0 + mt * 16 + ln) * 8]);
    half8 b[8];
#pragma unroll
    for (int nt = 0; nt < 8; nt++)
      b[nt] = *(const half8*)(&Ws[(kg * 128 + nt * 16 + ln) * 8]);
#pragma unroll
    for (int mt = 0; mt < 2; mt++)
#pragma unroll
      for (int nt = 0; nt < 8; nt++)
        acc[mt][nt] =
            __builtin_amdgcn_mfma_f32_16x16x32_f16(a[mt], b[nt], acc[mt][nt], 0, 0, 0);
  }

#pragma unroll
  for (int mt = 0; mt < 2; mt++) {
#pragma unroll
    for (int r = 0; r < 4; r++) {
      int grow = rowBase + m0 + mt * 16 + q * 4 + r;
      if (grow < n) {
#pragma unroll
        for (int nt = 0; nt < 8; nt++)
          Hh[(size_t)grow * 128 + nt * 16 + ln] = f2h(acc[mt][nt][r]);
      }
    }
  }
}

// ---------------------------------------------------------------------------
// PAIRED-EDGE aggregation over fp16 h — NAMED SCALARS ONLY (no arrays: any
// array indexed by a lane-dependent value is demoted to scratch/LDS on
// gfx950 — R5/R6 post-mortems). One wave per node; lanes 0-31 = even edges,
// lanes 32-63 = odd edges; each lane loads uint2 (4 channels) so one gather
// instruction = 32 lanes/edge (half of R4's 64) x 2 edges = 512 B.
// 4 gathers in flight; next group's col/wgt prefetched into named scalars.
// Halves combined via shfl_xor(32); lanes 0-31 write.
// last=0: fp16-packed out + BN stats.  last=1: fp32 out, no stats.
// ---------------------------------------------------------------------------
__global__ __launch_bounds__(256) void k_agg(const unsigned int* __restrict__ hb,
                                             const int* __restrict__ row_ptr,
                                             const int* __restrict__ col,
                                             const float* __restrict__ wgt,
                                             const float* __restrict__ dinv,
                                             const float* __restrict__ bias,
                                             void* __restrict__ out,
                                             float* __restrict__ stats, int n,
                                             int last) {
  __shared__ float lsum[128], lsq[128];
  const int t = threadIdx.x;
  if (!last) {
    if (t < 128) {
      lsum[t] = 0.f;
      lsq[t] = 0.f;
    }
    __syncthreads();
  }
  const int wave = t >> 6, lane = t & 63;
  const int p = lane & 31;   // position within half (channels 4p..4p+3)
  const int hi = lane >> 5;  // 0 = even edges, 1 = odd edges
  const uint2* hbp = (const uint2*)hb;

  for (int nd = blockIdx.x * 4 + wave; nd < n; nd += gridDim.x * 4) {
    float di = dinv[nd];
    float wself = hi ? 0.f : di * di;  // self-loop counted once (half 0)
    uint2 sv = hbp[(size_t)nd * 32 + p];
    float a0 = wself * h2f(sv.x & 0xffff), a1 = wself * h2f(sv.x >> 16);
    float a2 = wself * h2f(sv.y & 0xffff), a3 = wself * h2f(sv.y >> 16);
    float b0 = 0.f, b1 = 0.f, b2 = 0.f, b3 = 0.f;
    int e0 = row_ptr[nd], e1 = row_ptr[nd + 1];  // length multiple of 8
    if (e0 < e1) {
      int c0 = col[e0 + 0], c1 = col[e0 + 1], c2 = col[e0 + 2], c3 = col[e0 + 3];
      int c4 = col[e0 + 4], c5 = col[e0 + 5], c6 = col[e0 + 6], c7 = col[e0 + 7];
      float f0 = wgt[e0 + 0], f1 = wgt[e0 + 1], f2 = wgt[e0 + 2], f3 = wgt[e0 + 3];
      float f4 = wgt[e0 + 4], f5 = wgt[e0 + 5], f6 = wgt[e0 + 6], f7 = wgt[e0 + 7];
      for (int e = e0; e < e1; e += 8) {
        int en = e + 8;
        int ep = (en < e1) ? en : e;  // clamp: reload current group if last
        int n0 = col[ep + 0], n1 = col[ep + 1], n2 = col[ep + 2], n3 = col[ep + 3];
        int n4 = col[ep + 4], n5 = col[ep + 5], n6 = col[ep + 6], n7 = col[ep + 7];
        float g0 = wgt[ep + 0], g1 = wgt[ep + 1], g2 = wgt[ep + 2], g3 = wgt[ep + 3];
        float g4 = wgt[ep + 4], g5 = wgt[ep + 5], g6 = wgt[ep + 6], g7 = wgt[ep + 7];
        // per-half edge select: named scalars -> v_cndmask, stays in regs
        int rA = hi ? c1 : c0;
        int rB = hi ? c3 : c2;
        int rC = hi ? c5 : c4;
        int rD = hi ? c7 : c6;
        uint2 u0 = hbp[(size_t)rA * 32 + p];
        uint2 u1 = hbp[(size_t)rB * 32 + p];
        uint2 u2 = hbp[(size_t)rC * 32 + p];
        uint2 u3 = hbp[(size_t)rD * 32 + p];
        float wa = hi ? f1 : f0;
        float wb = hi ? f3 : f2;
        float wc = hi ? f5 : f4;
        float wd = hi ? f7 : f6;
        a0 += wa * h2f(u0.x & 0xffff);
        a1 += wa * h2f(u0.x >> 16);
        a2 += wa * h2f(u0.y & 0xffff);
        a3 += wa * h2f(u0.y >> 16);
        b0 += wb * h2f(u1.x & 0xffff);
        b1 += wb * h2f(u1.x >> 16);
        b2 += wb * h2f(u1.y & 0xffff);
        b3 += wb * h2f(u1.y >> 16);
        a0 += wc * h2f(u2.x & 0xffff);
        a1 += wc * h2f(u2.x >> 16);
        a2 += wc * h2f(u2.y & 0xffff);
        a3 += wc * h2f(u2.y >> 16);
        b0 += wd * h2f(u3.x & 0xffff);
        b1 += wd * h2f(u3.x >> 16);
        b2 += wd * h2f(u3.y & 0xffff);
        b3 += wd * h2f(u3.y >> 16);
        c0 = n0; c1 = n1; c2 = n2; c3 = n3;
        c4 = n4; c5 = n5; c6 = n6; c7 = n7;
        f0 = g0; f1 = g1; f2 = g2; f3 = g3;
        f4 = g4; f5 = g5; f6 = g6; f7 = g7;
      }
    }
    a0 += b0; a1 += b1; a2 += b2; a3 += b3;
    // combine odd/even halves
    a0 += __shfl_xor(a0, 32);
    a1 += __shfl_xor(a1, 32);
    a2 += __shfl_xor(a2, 32);
    a3 += __shfl_xor(a3, 32);
    if (!hi) {
      float4 bv = *(const float4*)(bias + p * 4);
      a0 += bv.x;
      a1 += bv.y;
      a2 += bv.z;
      a3 += bv.w;
      if (last) {
        float4 o = {a0, a1, a2, a3};
        *(float4*)((float*)out + (size_t)nd * 128 + p * 4) = o;
      } else {
        uint2 o;
        o.x = packh(a0, a1);
        o.y = packh(a2, a3);
        *(uint2*)((unsigned int*)out + (size_t)nd * 64 + p * 2) = o;
        atomicAdd(&lsum[p * 4 + 0], a0);
        atomicAdd(&lsum[p * 4 + 1], a1);
        atomicAdd(&lsum[p * 4 + 2], a2);
        atomicAdd(&lsum[p * 4 + 3], a3);
        atomicAdd(&lsq[p * 4 + 0], a0 * a0);
        atomicAdd(&lsq[p * 4 + 1], a1 * a1);
        atomicAdd(&lsq[p * 4 + 2], a2 * a2);
        atomicAdd(&lsq[p * 4 + 3], a3 * a3);
      }
    }
  }
  if (!last) {
    __syncthreads();
    if (t < 128) {
      atomicAdd(&stats[t], lsum[t]);
      atomicAdd(&stats[128 + t], lsq[t]);
    }
  }
}

// ---------------------------------------------------------------------------
extern "C" void kernel_launch(void* const* d_in, const int* in_sizes, int n_in,
                              void* d_out, int out_size, void* d_ws, size_t ws_size,
                              hipStream_t stream) {
  const float* x_in = (const float*)d_in[0];
  const int* ei = (const int*)d_in[1];
  const float* W0 = (const float*)d_in[2];
  const float* b0 = (const float*)d_in[3];
  const float* Wmid = (const float*)d_in[4];
  const float* bmid = (const float*)d_in[5];
  const float* Wlast = (const float*)d_in[6];
  const float* blast = (const float*)d_in[7];
  const float* gamma = (const float*)d_in[8];
  const float* beta = (const float*)d_in[9];

  const int n = in_sizes[0] / D;  // 100000
  const int e = in_sizes[1] / 2;  // 1600000
  const int ec = e + 8 * n;       // padded-edge capacity (worst case)

  // ---- workspace carve-out ----
  char* ws = (char*)d_ws;
  size_t off = 0;
  auto alloc = [&](size_t bytes) -> void* {
    void* p = ws + off;
    off += (bytes + 255) & ~(size_t)255;
    return p;
  };
  unsigned int* XhA = (unsigned int*)alloc((size_t)n * 64 * 4);  // fp16 x ping
  unsigned int* XhB = (unsigned int*)alloc((size_t)n * 64 * 4);  // fp16 x pong
  unsigned int* Hh = (unsigned int*)alloc((size_t)n * 64 * 4);   // fp16 h
  unsigned int* Ag = (unsigned int*)alloc((size_t)n * 64 * 4);   // fp16 aggout
  ushort_t* Wf = (ushort_t*)alloc((size_t)6 * 16384 * 2);
  int* row_ptr = (int*)alloc((size_t)(n + 1) * 4);
  int* excl = (int*)alloc((size_t)n * 4);
  float* dinv = (float*)alloc((size_t)n * 4);
  int* bsum = (int*)alloc(1024);
  int* flag = (int*)alloc(256);
  // zeroed region: col | wgt | cnt | fill | stats  (single memset)
  char* zbase = ws + off;
  int* col = (int*)alloc((size_t)ec * 4);
  float* wgt = (float*)alloc((size_t)ec * 4);
  int* cnt = (int*)alloc((size_t)n * 4);
  int* fill = (int*)alloc((size_t)n * 4);
  float* stats = (float*)alloc(5 * 256 * 4);
  size_t zbytes = (size_t)((ws + off) - zbase);
  hipMemsetAsync(zbase, 0, zbytes, stream);

  // ---- graph prep ----
  k_detect<<<1, 64, 0, stream>>>(ei, flag);
  int eb = (e + 255) / 256;
  k_hist<<<eb, 256, 0, stream>>>(ei, cnt, flag, e);
  int nb1024 = (n + 1023) / 1024;
  k_scan1<<<nb1024, 256, 0, stream>>>(cnt, excl, bsum, n);
  k_scan2<<<1, 64, 0, stream>>>(bsum, nb1024, row_ptr, n);
  int nb256 = (n + 255) / 256;
  k_scan3<<<nb256, 256, 0, stream>>>(excl, bsum, row_ptr, n);
  k_dinv<<<nb256, 256, 0, stream>>>(cnt, dinv, n);
  k_scatter<<<eb, 256, 0, stream>>>(ei, row_ptr, fill, dinv, col, wgt, flag, e);
  k_wconv<<<(6 * 16384 + 255) / 256, 256, 0, stream>>>(W0, Wmid, Wlast, Wf);

  // ---- layers ----
  const int gemm_blocks = (n + 127) / 128;
  const int agg_blocks = 2048;

  // layer 0
  k_gemm<<<gemm_blocks, 256, 0, stream>>>(x_in, Wf, (ushort_t*)Hh, nullptr,
                                          nullptr, nullptr, nullptr, nullptr, n, 0);
  k_agg<<<agg_blocks, 256, 0, stream>>>(Hh, row_ptr, col, wgt, dinv, b0, Ag,
                                        stats, n, 0);
  // layers 1..4 (gemm_L fuses BN/relu/residual of layer L-1)
  unsigned int* xprev = nullptr;
  unsigned int* xnew = XhA;
  for (int L = 1; L <= 4; L++) {
    const float* bL = bmid + (size_t)(L - 1) * D;
    k_gemm<<<gemm_blocks, 256, 0, stream>>>(
        Ag, Wf + (size_t)L * 16384, (ushort_t*)Hh, xnew, xprev,
        stats + (L - 1) * 256, gamma + (L - 1) * D, beta + (L - 1) * D, n,
        (L == 1) ? 1 : 2);
    k_agg<<<agg_blocks, 256, 0, stream>>>(Hh, row_ptr, col, wgt, dinv, bL, Ag,
                                          stats + L * 256, n, 0);
    xprev = xnew;
    xnew = (xnew == XhA) ? XhB : XhA;
  }
  // output layer (gemm_5 fuses BN/relu/residual of layer 4)
  k_gemm<<<gemm_blocks, 256, 0, stream>>>(Ag, Wf + (size_t)5 * 16384,
                                          (ushort_t*)Hh, xnew, xprev,
                                          stats + 4 * 256, gamma + 4 * D,
                                          beta + 4 * D, n, 2);
  k_agg<<<agg_blocks, 256, 0, stream>>>(Hh, row_ptr, col, wgt, dinv, blast,
                                        d_out, nullptr, n, 1);
}